// Round 1
// baseline (724.752 us; speedup 1.0000x reference)
//
#include <hip/hip_runtime.h>
#include <math.h>

#ifndef M_PI
#define M_PI 3.14159265358979323846
#endif

// SPH solver step (SolverInTheLoop_17042430230548)
// Reference facts exploited:
//   * v_i - u_i == 0  -> transport stress term Ar == 0 exactly
//   * p_bg_i == 0     -> dvdt == 0 exactly (out cols 5..7 stay zero)
//   * eta_i == eta_j == 0.01 -> eta_ij is a compile-time constant
static constexpr float kSigma = (float)(3.0 / 359.0 / M_PI);  // H = 1
static constexpr float kPRef  = 100.0f;
static constexpr float kEps   = 1e-8f;

__device__ __forceinline__ float pow5f(float t) { float t2 = t * t; return t2 * t2 * t; }
__device__ __forceinline__ float pow4f(float t) { float t2 = t * t; return t2 * t2; }

// Pack r, v ([N,3] fp32) into float4-padded arrays so edge-side gathers are a
// single 16B transaction per particle instead of three 4B ones.
__global__ void k_pack(const float* __restrict__ r, const float* __restrict__ v,
                       float4* __restrict__ r4, float4* __restrict__ v4, int n) {
    int i = blockIdx.x * blockDim.x + threadIdx.x;
    if (i >= n) return;
    r4[i] = make_float4(r[3 * i], r[3 * i + 1], r[3 * i + 2], 0.f);
    v4[i] = make_float4(v[3 * i], v[3 * i + 1], v[3 * i + 2], 0.f);
}

// Pass 1 over edges: density scatter-add.
__global__ void k_rho(const float4* __restrict__ r4, const int* __restrict__ i_s,
                      const int* __restrict__ j_s, float* __restrict__ rho, int E) {
    int e = blockIdx.x * blockDim.x + threadIdx.x;
    if (e >= E) return;
    int i = i_s[e], j = j_s[e];
    float4 ri = r4[i], rj = r4[j];
    float dx = ri.x - rj.x, dy = ri.y - rj.y, dz = ri.z - rj.z;
    float d = sqrtf(dx * dx + dy * dy + dz * dz);
    float t1 = fmaxf(1.f - d, 0.f);
    float t2 = fmaxf(2.f - d, 0.f);
    float t3 = fmaxf(3.f - d, 0.f);
    float w = kSigma * (pow5f(t3) - 6.f * pow5f(t2) + 15.f * pow5f(t1));
    atomicAdd(&rho[i], w);
}

// Per-particle: finalize rho/p, precompute 1/rho^2 once (vs per edge-side),
// and write output columns 0 (rho) and 1 (p).
__global__ void k_state(const float* __restrict__ rho, float4* __restrict__ rp4,
                        float* __restrict__ out, int n) {
    int i = blockIdx.x * blockDim.x + threadIdx.x;
    if (i >= n) return;
    float rh = rho[i];
    float p = kPRef * (rh - 1.0f);
    float inv = 1.0f / rh;
    rp4[i] = make_float4(rh, p, inv * inv, 0.f);
    out[(size_t)i * 8 + 0] = rh;
    out[(size_t)i * 8 + 1] = p;
}

// Pass 2 over edges: acceleration scatter-add into out cols 2..4.
__global__ void k_acc(const float4* __restrict__ r4, const float4* __restrict__ v4,
                      const float4* __restrict__ rp4, const int* __restrict__ i_s,
                      const int* __restrict__ j_s, float* __restrict__ out, int E) {
    int e = blockIdx.x * blockDim.x + threadIdx.x;
    if (e >= E) return;
    int i = i_s[e], j = j_s[e];
    float4 ri = r4[i], rj = r4[j];
    float dx = ri.x - rj.x, dy = ri.y - rj.y, dz = ri.z - rj.z;
    float d = sqrtf(dx * dx + dy * dy + dz * dz);
    float t1 = fmaxf(1.f - d, 0.f);
    float t2 = fmaxf(2.f - d, 0.f);
    float t3 = fmaxf(3.f - d, 0.f);
    float gw = kSigma * (-5.f * pow4f(t3) + 30.f * pow4f(t2) - 75.f * pow4f(t1));

    float4 si = rp4[i], sj = rp4[j];              // (rho, p, 1/rho^2, _)
    float p_ij = (sj.x * si.y + si.x * sj.y) / (si.x + sj.x);
    float c = (si.z + sj.z) * gw / (d + kEps);
    const float eta_ij = 2.0f * 0.01f * 0.01f / (0.01f + 0.01f + 1e-8f);

    float4 ui = v4[i], uj = v4[j];
    float ax = c * (eta_ij * (ui.x - uj.x) - p_ij * dx);
    float ay = c * (eta_ij * (ui.y - uj.y) - p_ij * dy);
    float az = c * (eta_ij * (ui.z - uj.z) - p_ij * dz);

    float* o = out + (size_t)i * 8 + 2;
    atomicAdd(o + 0, ax);
    atomicAdd(o + 1, ay);
    atomicAdd(o + 2, az);
}

extern "C" void kernel_launch(void* const* d_in, const int* in_sizes, int n_in,
                              void* d_out, int out_size, void* d_ws, size_t ws_size,
                              hipStream_t stream) {
    const float* r = (const float*)d_in[0];
    const float* v = (const float*)d_in[1];
    const int* i_s = (const int*)d_in[2];
    const int* j_s = (const int*)d_in[3];
    int n = in_sizes[0] / 3;
    int E = in_sizes[2];
    float* out = (float*)d_out;

    char* ws = (char*)d_ws;
    float4* r4  = (float4*)ws; ws += (size_t)n * 16;
    float4* v4  = (float4*)ws; ws += (size_t)n * 16;
    float4* rp4 = (float4*)ws; ws += (size_t)n * 16;
    float*  rho = (float*)ws;  ws += (size_t)n * 4;

    hipMemsetAsync(rho, 0, (size_t)n * 4, stream);
    hipMemsetAsync(d_out, 0, (size_t)out_size * sizeof(float), stream);

    const int bs = 256;
    k_pack<<<(n + bs - 1) / bs, bs, 0, stream>>>(r, v, r4, v4, n);
    k_rho<<<(E + bs - 1) / bs, bs, 0, stream>>>(r4, i_s, j_s, rho, E);
    k_state<<<(n + bs - 1) / bs, bs, 0, stream>>>(rho, rp4, out, n);
    k_acc<<<(E + bs - 1) / bs, bs, 0, stream>>>(r4, v4, rp4, i_s, j_s, out, E);
}

// Round 2
// 306.685 us; speedup vs baseline: 2.3632x; 2.3632x over previous
//
#include <hip/hip_runtime.h>
#include <math.h>

#ifndef M_PI
#define M_PI 3.14159265358979323846
#endif

// SPH solver step — pull formulation via counting sort by receiver.
// Reference facts exploited:
//   * v_i - u_i == 0  -> transport stress term Ar == 0 exactly
//   * p_bg_i == 0     -> dvdt == 0 exactly (out cols 5..7 zero)
//   * eta_i == eta_j  -> eta_ij is a compile-time constant
//   * p = 100*(rho-1) -> p_j derivable from rho_j, so the acc-pass gather is
//     a single 16B record {v, rho} per neighbor.
static constexpr float kSigma = (float)(3.0 / 359.0 / M_PI);  // H = 1
static constexpr float kPRef  = 100.0f;
static constexpr float kEps   = 1e-8f;
static constexpr float kEta   = (float)(2.0 * 0.01 * 0.01 / (0.01 + 0.01 + 1e-8));

__device__ __forceinline__ float pow5f(float t) { float t2 = t * t; return t2 * t2 * t; }
__device__ __forceinline__ float pow4f(float t) { float t2 = t * t; return t2 * t2; }

// ---------------- pack positions into 16B records ----------------
__global__ void k_pack(const float* __restrict__ r, float4* __restrict__ pos4, int n) {
    int i = blockIdx.x * blockDim.x + threadIdx.x;
    if (i >= n) return;
    pos4[i] = make_float4(r[3 * i], r[3 * i + 1], r[3 * i + 2], 0.f);
}

// ---------------- counting sort: rank assignment (the only atomic pass) ------
__global__ void k_rank(const int* __restrict__ i_s, int* __restrict__ count,
                       int* __restrict__ rank, int E) {
    int e = blockIdx.x * blockDim.x + threadIdx.x;
    if (e >= E) return;
    rank[e] = atomicAdd(&count[i_s[e]], 1);
}

// ---------------- 3-kernel exclusive scan over count[n] ----------------
__global__ void k_scan_block(const int* __restrict__ count, int* __restrict__ offset,
                             int* __restrict__ bsum, int n) {
    __shared__ int s[256];
    int t = threadIdx.x;
    int i = blockIdx.x * 256 + t;
    int x = (i < n) ? count[i] : 0;
    s[t] = x;
    __syncthreads();
    for (int d = 1; d < 256; d <<= 1) {
        int v = (t >= d) ? s[t - d] : 0;
        __syncthreads();
        s[t] += v;
        __syncthreads();
    }
    if (i < n) offset[i] = s[t] - x;            // block-local exclusive
    if (t == 255) bsum[blockIdx.x] = s[255];    // block total
}

__global__ void k_scan_bsums(const int* __restrict__ bsum, int* __restrict__ bscan, int nb) {
    __shared__ int s[512];  // requires nb <= 512 (n=100k -> nb=391)
    int t = threadIdx.x;
    int x = (t < nb) ? bsum[t] : 0;
    s[t] = x;
    __syncthreads();
    for (int d = 1; d < 512; d <<= 1) {
        int v = (t >= d) ? s[t - d] : 0;
        __syncthreads();
        s[t] += v;
        __syncthreads();
    }
    if (t < nb) bscan[t] = s[t] - x;            // exclusive
}

__global__ void k_scan_add(int* __restrict__ offset, const int* __restrict__ bscan,
                           int n, int E) {
    int i = blockIdx.x * blockDim.x + threadIdx.x;
    if (i < n) offset[i] += bscan[i >> 8];
    if (i == 0) offset[n] = E;
}

// ---------------- scatter j into receiver-sorted order (no atomic) ----------
__global__ void k_scatter(const int* __restrict__ i_s, const int* __restrict__ j_s,
                          const int* __restrict__ rank, const int* __restrict__ offset,
                          int* __restrict__ sortedJ, int E) {
    int e = blockIdx.x * blockDim.x + threadIdx.x;
    if (e >= E) return;
    sortedJ[offset[i_s[e]] + rank[e]] = j_s[e];
}

// ---------------- pass 1: density, half-wave (32 lanes) per particle --------
__global__ void k_rho(const float4* __restrict__ pos4, const int* __restrict__ sortedJ,
                      const int* __restrict__ offset, float* __restrict__ rho,
                      float4* __restrict__ drdj, int use_drdj, int n) {
    int p = (int)((blockIdx.x * (size_t)blockDim.x + threadIdx.x) >> 5);
    int lane = threadIdx.x & 31;
    if (p >= n) return;                 // uniform across each 32-lane group
    float4 ri = pos4[p];                // broadcast (same address)
    int s = offset[p], e = offset[p + 1];
    float acc = 0.f;
    for (int k = s + lane; k < e; k += 32) {
        int j = sortedJ[k];
        float4 rj = pos4[j];            // the divergent gather
        float dx = ri.x - rj.x, dy = ri.y - rj.y, dz = ri.z - rj.z;
        float d = sqrtf(dx * dx + dy * dy + dz * dz);
        float t1 = fmaxf(1.f - d, 0.f);
        float t2 = fmaxf(2.f - d, 0.f);
        float t3 = fmaxf(3.f - d, 0.f);
        acc += kSigma * (pow5f(t3) - 6.f * pow5f(t2) + 15.f * pow5f(t1));
        if (use_drdj) drdj[k] = make_float4(dx, dy, dz, __int_as_float(j));
    }
    for (int o = 16; o; o >>= 1) acc += __shfl_down(acc, o, 32);
    if (lane == 0) rho[p] = acc;
}

// ---------------- per-particle state: finalize rho/p, pack {v, rho} ---------
__global__ void k_state(const float* __restrict__ v, const float* __restrict__ rho,
                        float4* __restrict__ svr4, float* __restrict__ out, int n) {
    int i = blockIdx.x * blockDim.x + threadIdx.x;
    if (i >= n) return;
    float rh = rho[i];
    svr4[i] = make_float4(v[3 * i], v[3 * i + 1], v[3 * i + 2], rh);
    float* o = out + (size_t)i * 8;
    o[0] = rh;
    o[1] = kPRef * (rh - 1.0f);
    o[5] = 0.f; o[6] = 0.f; o[7] = 0.f;   // dvdt == 0 exactly
}

// ---------------- pass 2: acceleration, half-wave per particle --------------
__global__ void k_acc(const float4* __restrict__ pos4, const float4* __restrict__ svr4,
                      const float4* __restrict__ drdj, const int* __restrict__ sortedJ,
                      const int* __restrict__ offset, float* __restrict__ out,
                      int use_drdj, int n) {
    int p = (int)((blockIdx.x * (size_t)blockDim.x + threadIdx.x) >> 5);
    int lane = threadIdx.x & 31;
    if (p >= n) return;
    float4 si = svr4[p];                // broadcast: {u_i, rho_i}
    float rho_i = si.w;
    float p_i = kPRef * (rho_i - 1.0f);
    float inv_i = 1.0f / rho_i;
    float inv2_i = inv_i * inv_i;
    float4 ri;
    if (!use_drdj) ri = pos4[p];
    int s = offset[p], e = offset[p + 1];
    float ax = 0.f, ay = 0.f, az = 0.f;
    for (int k = s + lane; k < e; k += 32) {
        float dx, dy, dz;
        int j;
        if (use_drdj) {
            float4 f = drdj[k];         // coalesced
            dx = f.x; dy = f.y; dz = f.z; j = __float_as_int(f.w);
        } else {
            j = sortedJ[k];
            float4 rj = pos4[j];        // extra divergent gather (fallback)
            dx = ri.x - rj.x; dy = ri.y - rj.y; dz = ri.z - rj.z;
        }
        float4 sj = svr4[j];            // the divergent gather: {u_j, rho_j}
        float rho_j = sj.w;
        float p_j = kPRef * (rho_j - 1.0f);
        float inv_j = 1.0f / rho_j;
        float d = sqrtf(dx * dx + dy * dy + dz * dz);
        float t1 = fmaxf(1.f - d, 0.f);
        float t2 = fmaxf(2.f - d, 0.f);
        float t3 = fmaxf(3.f - d, 0.f);
        float gw = kSigma * (-5.f * pow4f(t3) + 30.f * pow4f(t2) - 75.f * pow4f(t1));
        float c = (inv2_i + inv_j * inv_j) * gw / (d + kEps);
        float p_ij = (rho_j * p_i + rho_i * p_j) / (rho_i + rho_j);
        ax += c * (kEta * (si.x - sj.x) - p_ij * dx);
        ay += c * (kEta * (si.y - sj.y) - p_ij * dy);
        az += c * (kEta * (si.z - sj.z) - p_ij * dz);
    }
    for (int o = 16; o; o >>= 1) {
        ax += __shfl_down(ax, o, 32);
        ay += __shfl_down(ay, o, 32);
        az += __shfl_down(az, o, 32);
    }
    if (lane == 0) {
        float* o = out + (size_t)p * 8 + 2;
        o[0] = ax; o[1] = ay; o[2] = az;
    }
}

// ---------------- launch ----------------
static inline char* wcarve(char*& ws, size_t bytes) {
    char* p = ws;
    ws += (bytes + 255) & ~(size_t)255;
    return p;
}

extern "C" void kernel_launch(void* const* d_in, const int* in_sizes, int n_in,
                              void* d_out, int out_size, void* d_ws, size_t ws_size,
                              hipStream_t stream) {
    const float* r = (const float*)d_in[0];
    const float* v = (const float*)d_in[1];
    const int* i_s = (const int*)d_in[2];
    const int* j_s = (const int*)d_in[3];
    int n = in_sizes[0] / 3;
    int E = in_sizes[2];
    float* out = (float*)d_out;

    char* ws = (char*)d_ws;
    char* ws_end = ws + ws_size;
    float4* pos4   = (float4*)wcarve(ws, (size_t)n * 16);
    float4* svr4   = (float4*)wcarve(ws, (size_t)n * 16);
    float*  rho    = (float*)wcarve(ws, (size_t)n * 4);
    int*    count  = (int*)wcarve(ws, (size_t)n * 4);
    int*    offset = (int*)wcarve(ws, (size_t)(n + 1) * 4);
    int nb = (n + 255) / 256;          // 391 for n=100k (k_scan_bsums needs <=512)
    int*    bsum   = (int*)wcarve(ws, (size_t)nb * 4);
    int*    bscan  = (int*)wcarve(ws, (size_t)nb * 4);
    int*    rank   = (int*)wcarve(ws, (size_t)E * 4);
    int*    sortedJ= (int*)wcarve(ws, (size_t)E * 4);
    float4* drdj   = nullptr;
    int use_drdj = 0;
    if (ws + (size_t)E * 16 <= ws_end) {
        drdj = (float4*)wcarve(ws, (size_t)E * 16);
        use_drdj = 1;
    }

    hipMemsetAsync(count, 0, (size_t)n * 4, stream);

    const int bs = 256;
    int gn = (n + bs - 1) / bs;
    int gE = (E + bs - 1) / bs;
    int gp = (n + 7) / 8;              // 8 half-waves (particles) per 256-thread block

    k_pack<<<gn, bs, 0, stream>>>(r, pos4, n);
    k_rank<<<gE, bs, 0, stream>>>(i_s, count, rank, E);
    k_scan_block<<<nb, 256, 0, stream>>>(count, offset, bsum, n);
    k_scan_bsums<<<1, 512, 0, stream>>>(bsum, bscan, nb);
    k_scan_add<<<gn, bs, 0, stream>>>(offset, bscan, n, E);
    k_scatter<<<gE, bs, 0, stream>>>(i_s, j_s, rank, offset, sortedJ, E);
    k_rho<<<gp, bs, 0, stream>>>(pos4, sortedJ, offset, rho, drdj, use_drdj, n);
    k_state<<<gn, bs, 0, stream>>>(v, rho, svr4, out, n);
    k_acc<<<gp, bs, 0, stream>>>(pos4, svr4, drdj, sortedJ, offset, out, use_drdj, n);
}

// Round 3
// 208.982 us; speedup vs baseline: 3.4680x; 1.4675x over previous
//
#include <hip/hip_runtime.h>
#include <math.h>

#ifndef M_PI
#define M_PI 3.14159265358979323846
#endif

// SPH solver step — pull formulation, zero global atomics.
// Build: two-level LDS bucket sort by receiver (coarse bin i>>SHIFT, then fine
// slot within bin), producing sortedJ[] grouped by receiver + offset[] CSR.
// Reference facts exploited:
//   * v_i - u_i == 0  -> transport stress term Ar == 0 exactly
//   * p_bg_i == 0     -> dvdt == 0 exactly (out cols 5..7 zero via memset)
//   * eta_i == eta_j  -> eta_ij compile-time constant
//   * p = 100*(rho-1) -> particle record {r,rho | v,p} is 32B = 1 cache line
static constexpr float kSigma = (float)(3.0 / 359.0 / M_PI);  // H = 1
static constexpr float kPRef  = 100.0f;
static constexpr float kEps   = 1e-8f;
static constexpr float kEta   = (float)(2.0 * 0.01 * 0.01 / (0.01 + 0.01 + 1e-8));

#define CHUNKA 8192   // edges per block in the coarse split (nbA = ceil(E/CHUNKA))

__device__ __forceinline__ float pow5f(float t) { float t2 = t * t; return t2 * t2 * t; }
__device__ __forceinline__ float pow4f(float t) { float t2 = t * t; return t2 * t2; }

// ---------------- pack positions; also plant offset[n] = E ----------------
__global__ void k_pack(const float* __restrict__ r, float4* __restrict__ pos4,
                       int* __restrict__ offset, int n, int E) {
    int i = blockIdx.x * blockDim.x + threadIdx.x;
    if (i == 0) offset[n] = E;
    if (i >= n) return;
    pos4[i] = make_float4(r[3 * i], r[3 * i + 1], r[3 * i + 2], 0.f);
}

// ---------------- coarse histogram: LDS atomics only ----------------
__global__ void k_hist(const int* __restrict__ i_s, int* __restrict__ ghist,
                       int nbA, int E, int shift) {
    __shared__ int h[256];
    int t = threadIdx.x, blk = blockIdx.x;
    h[t] = 0;
    __syncthreads();
    int base = blk * CHUNKA;
    int end = min(base + CHUNKA, E);
    for (int k = base + t; k < end; k += 256)
        atomicAdd(&h[i_s[k] >> shift], 1);
    __syncthreads();
    ghist[t * nbA + blk] = h[t];   // bin-major for the scan
}

// ---------------- 3-kernel exclusive scan over m elements ----------------
__global__ void k_scan_block(const int* __restrict__ in, int* __restrict__ out,
                             int* __restrict__ bsum, int m) {
    __shared__ int s[256];
    int t = threadIdx.x;
    int i = blockIdx.x * 256 + t;
    int x = (i < m) ? in[i] : 0;
    s[t] = x;
    __syncthreads();
    for (int d = 1; d < 256; d <<= 1) {
        int v = (t >= d) ? s[t - d] : 0;
        __syncthreads();
        s[t] += v;
        __syncthreads();
    }
    if (i < m) out[i] = s[t] - x;            // block-local exclusive
    if (t == 255) bsum[blockIdx.x] = s[255];
}

__global__ void k_scan_bsums(const int* __restrict__ bsum, int* __restrict__ bscan, int nb) {
    __shared__ int s[512];  // requires nb <= 512
    int t = threadIdx.x;
    int x = (t < nb) ? bsum[t] : 0;
    s[t] = x;
    __syncthreads();
    for (int d = 1; d < 512; d <<= 1) {
        int v = (t >= d) ? s[t - d] : 0;
        __syncthreads();
        s[t] += v;
        __syncthreads();
    }
    if (t < nb) bscan[t] = s[t] - x;
}

__global__ void k_scan_add(int* __restrict__ a, const int* __restrict__ bscan, int m) {
    int i = blockIdx.x * blockDim.x + threadIdx.x;
    if (i < m) a[i] += bscan[i >> 8];
}

// ---------------- coarse split: scatter (i,j) pairs into coarse bins --------
__global__ void k_split(const int* __restrict__ i_s, const int* __restrict__ j_s,
                        const int* __restrict__ gscan, int2* __restrict__ pairs,
                        int nbA, int E, int shift) {
    __shared__ int cur[256];
    int t = threadIdx.x, blk = blockIdx.x;
    cur[t] = gscan[t * nbA + blk];
    __syncthreads();
    int base = blk * CHUNKA;
    int end = min(base + CHUNKA, E);
    for (int k = base + t; k < end; k += 256) {
        int i = i_s[k];
        int pos = atomicAdd(&cur[i >> shift], 1);   // LDS atomic
        pairs[pos] = make_int2(i, j_s[k]);
    }
}

// ---------------- fine sort within each coarse bin ----------------
// One block (512 threads) per coarse bin; fine slots = 1<<shift <= 512.
__global__ void k_binsort(const int2* __restrict__ pairs, const int* __restrict__ gscan,
                          int* __restrict__ sortedJ, int* __restrict__ offset,
                          int nbA, int n, int E, int shift) {
    __shared__ int h[512];
    __shared__ int se[2];
    int b = blockIdx.x, t = threadIdx.x;
    h[t] = 0;
    if (t == 0) {
        se[0] = gscan[b * nbA];
        int idx = (b + 1) * nbA;
        se[1] = (idx < 256 * nbA) ? gscan[idx] : E;
    }
    __syncthreads();
    int s = se[0], e = se[1];
    int lo = b << shift;
    for (int k = s + t; k < e; k += 512)
        atomicAdd(&h[pairs[k].x - lo], 1);
    __syncthreads();
    int x = h[t];
    for (int d = 1; d < 512; d <<= 1) {           // inclusive scan (read-barrier-write)
        int v = (t >= d) ? h[t - d] : 0;
        __syncthreads();
        h[t] += v;
        __syncthreads();
    }
    int excl = h[t] - x;
    int i = lo + t;
    if (i < n) offset[i] = s + excl;              // CSR row starts, coalesced
    __syncthreads();
    h[t] = s + excl;                              // fine cursors
    __syncthreads();
    for (int k = s + t; k < e; k += 512) {
        int2 pr = pairs[k];
        int pos = atomicAdd(&h[pr.x - lo], 1);    // LDS atomic
        sortedJ[pos] = pr.y;                      // write within L2-hot bin window
    }
}

// ---------------- pass 1: density (fused per-particle state) ----------------
// Half-wave (32 lanes) per particle. Lane 0 writes out cols 0..1 and packs the
// 32B particle record {r.xyz, rho | v.xyz, p} used by k_acc.
__global__ void k_rho(const float4* __restrict__ pos4, const float* __restrict__ v,
                      const int* __restrict__ sortedJ, const int* __restrict__ offset,
                      float4* __restrict__ pv8, float* __restrict__ out, int n) {
    int p = (int)((blockIdx.x * (size_t)blockDim.x + threadIdx.x) >> 5);
    int lane = threadIdx.x & 31;
    if (p >= n) return;
    float4 ri = pos4[p];                // broadcast
    int s = offset[p], e = offset[p + 1];
    float acc = 0.f;
    for (int k = s + lane; k < e; k += 32) {
        int j = sortedJ[k];
        float4 rj = pos4[j];            // the divergent gather (1.6MB table, L2-hot)
        float dx = ri.x - rj.x, dy = ri.y - rj.y, dz = ri.z - rj.z;
        float d = sqrtf(dx * dx + dy * dy + dz * dz);
        float t1 = fmaxf(1.f - d, 0.f);
        float t2 = fmaxf(2.f - d, 0.f);
        float t3 = fmaxf(3.f - d, 0.f);
        acc += kSigma * (pow5f(t3) - 6.f * pow5f(t2) + 15.f * pow5f(t1));
    }
    for (int o = 16; o; o >>= 1) acc += __shfl_down(acc, o, 32);
    if (lane == 0) {
        float rh = acc;
        float pp = kPRef * (rh - 1.0f);
        pv8[2 * p]     = make_float4(ri.x, ri.y, ri.z, rh);
        pv8[2 * p + 1] = make_float4(v[3 * p], v[3 * p + 1], v[3 * p + 2], pp);
        float* o = out + (size_t)p * 8;
        o[0] = rh;
        o[1] = pp;
    }
}

// ---------------- pass 2: acceleration ----------------
// Half-wave per particle; one 32B record gather per neighbor (single cache line).
__global__ void k_acc(const float4* __restrict__ pv8, const int* __restrict__ sortedJ,
                      const int* __restrict__ offset, float* __restrict__ out, int n) {
    int p = (int)((blockIdx.x * (size_t)blockDim.x + threadIdx.x) >> 5);
    int lane = threadIdx.x & 31;
    if (p >= n) return;
    float4 ai = pv8[2 * p], bi = pv8[2 * p + 1];   // broadcast {r,rho | v,p}
    float rho_i = ai.w, p_i = bi.w;
    float inv_i = 1.0f / rho_i;
    float inv2_i = inv_i * inv_i;
    int s = offset[p], e = offset[p + 1];
    float ax = 0.f, ay = 0.f, az = 0.f;
    for (int k = s + lane; k < e; k += 32) {
        int j = sortedJ[k];
        float4 aj = pv8[2 * j];                    // same 64B line
        float4 bj = pv8[2 * j + 1];
        float rho_j = aj.w, p_j = bj.w;
        float dx = ai.x - aj.x, dy = ai.y - aj.y, dz = ai.z - aj.z;
        float d = sqrtf(dx * dx + dy * dy + dz * dz);
        float t1 = fmaxf(1.f - d, 0.f);
        float t2 = fmaxf(2.f - d, 0.f);
        float t3 = fmaxf(3.f - d, 0.f);
        float gw = kSigma * (-5.f * pow4f(t3) + 30.f * pow4f(t2) - 75.f * pow4f(t1));
        float inv_j = 1.0f / rho_j;
        float c = (inv2_i + inv_j * inv_j) * gw / (d + kEps);
        float p_ij = (rho_j * p_i + rho_i * p_j) / (rho_i + rho_j);
        ax += c * (kEta * (bi.x - bj.x) - p_ij * dx);
        ay += c * (kEta * (bi.y - bj.y) - p_ij * dy);
        az += c * (kEta * (bi.z - bj.z) - p_ij * dz);
    }
    for (int o = 16; o; o >>= 1) {
        ax += __shfl_down(ax, o, 32);
        ay += __shfl_down(ay, o, 32);
        az += __shfl_down(az, o, 32);
    }
    if (lane == 0) {
        float* o = out + (size_t)p * 8 + 2;
        o[0] = ax; o[1] = ay; o[2] = az;
    }
}

// ---------------- launch ----------------
static inline char* wcarve(char*& ws, size_t bytes) {
    char* p = ws;
    ws += (bytes + 255) & ~(size_t)255;
    return p;
}

extern "C" void kernel_launch(void* const* d_in, const int* in_sizes, int n_in,
                              void* d_out, int out_size, void* d_ws, size_t ws_size,
                              hipStream_t stream) {
    const float* r = (const float*)d_in[0];
    const float* v = (const float*)d_in[1];
    const int* i_s = (const int*)d_in[2];
    const int* j_s = (const int*)d_in[3];
    int n = in_sizes[0] / 3;
    int E = in_sizes[2];
    float* out = (float*)d_out;

    // coarse-bin shift: fine slots = 1<<shift <= 512, coarse bins <= 256
    int shift = 9;
    while ((((n - 1) >> shift) + 1) > 256) shift++;
    int cb_used = ((n - 1) >> shift) + 1;

    int nbA = (E + CHUNKA - 1) / CHUNKA;          // coarse-split blocks (391)
    int m = 256 * nbA;                            // histogram array length
    int nb2 = (m + 255) / 256;                    // scan blocks (<= 512 required)

    char* ws = (char*)d_ws;
    float4* pos4   = (float4*)wcarve(ws, (size_t)n * 16);
    float4* pv8    = (float4*)wcarve(ws, (size_t)n * 32);
    int*    offset = (int*)wcarve(ws, (size_t)(n + 1) * 4);
    int*    ghist  = (int*)wcarve(ws, (size_t)m * 4);
    int*    gscan  = (int*)wcarve(ws, (size_t)m * 4);
    int*    bsum   = (int*)wcarve(ws, (size_t)nb2 * 4);
    int*    bscan  = (int*)wcarve(ws, (size_t)nb2 * 4);
    int2*   pairs  = (int2*)wcarve(ws, (size_t)E * 8);
    int*    sortedJ= (int*)wcarve(ws, (size_t)E * 4);

    hipMemsetAsync(out, 0, (size_t)out_size * sizeof(float), stream);

    const int bs = 256;
    int gn = (n + bs - 1) / bs;
    int gp = (n + 7) / 8;                         // 8 half-waves per 256-thread block

    k_pack<<<gn, bs, 0, stream>>>(r, pos4, offset, n, E);
    k_hist<<<nbA, 256, 0, stream>>>(i_s, ghist, nbA, E, shift);
    k_scan_block<<<nb2, 256, 0, stream>>>(ghist, gscan, bsum, m);
    k_scan_bsums<<<1, 512, 0, stream>>>(bsum, bscan, nb2);
    k_scan_add<<<nb2, 256, 0, stream>>>(gscan, bscan, m);
    k_split<<<nbA, 256, 0, stream>>>(i_s, j_s, gscan, pairs, nbA, E, shift);
    k_binsort<<<cb_used, 512, 0, stream>>>(pairs, gscan, sortedJ, offset, nbA, n, E, shift);
    k_rho<<<gp, bs, 0, stream>>>(pos4, v, sortedJ, offset, pv8, out, n);
    k_acc<<<gp, bs, 0, stream>>>(pv8, sortedJ, offset, out, n);
}